// Round 1
// baseline (184731.409 us; speedup 1.0000x reference)
//
#include <hip/hip_runtime.h>
#include <hip/hip_bf16.h>
#include <math.h>

#define B_    64
#define T_    24
#define IND_  25
#define HID_  64
#define NPIX  625   // 25*25

__device__ __forceinline__ float sigmoidf_(float x) {
    return 1.f / (1.f + __expf(-x));
}
__device__ __forceinline__ float tanh_fast(float x) {
    return 2.f / (1.f + __expf(-2.f * x)) - 1.f;
}

__global__ __launch_bounds__(256) void fill_zero_kernel(float* __restrict__ p, int n) {
    int i = blockIdx.x * 256 + threadIdx.x;
    if (i < n) p[i] = 0.f;
}

// LayerNorm over the 25 channels for one timestep t: x(B,T,25,25,25) -> xn_t(B,25,25,25)
__global__ __launch_bounds__(256) void ln_t_kernel(
    const float* __restrict__ x, float* __restrict__ xn_t,
    const float* __restrict__ gamma, const float* __restrict__ beta, int t)
{
    int p = blockIdx.x * 256 + threadIdx.x;   // over B*625 positions
    if (p >= B_ * NPIX) return;
    int b = p / NPIX, hw = p % NPIX;
    const float* xp = x + ((size_t)(b * T_ + t) * IND_) * NPIX + hw;
    float v[IND_];
    float s = 0.f;
#pragma unroll
    for (int c = 0; c < IND_; ++c) { v[c] = xp[c * NPIX]; s += v[c]; }
    float mu = s * (1.f / IND_);
    float ss = 0.f;
#pragma unroll
    for (int c = 0; c < IND_; ++c) { float d = v[c] - mu; ss += d * d; }
    float rstd = rsqrtf(ss * (1.f / IND_) + 1e-5f);
    float* op = xn_t + (size_t)b * IND_ * NPIX + hw;
#pragma unroll
    for (int c = 0; c < IND_; ++c) op[c * NPIX] = (v[c] - mu) * rstd * gamma[c] + beta[c];
}

// One ConvLSTM timestep for BOTH branches (blockIdx.y: 0 -> dil=1, 1 -> dil=2).
// Each block: one (batch b, out-channel oc). Computes all 4 gates fused + state update.
// Weight layout in LDS: float4 wl[cin*9 + k9] = {w_i, w_f, w_o, w_g} for that tap.
__global__ __launch_bounds__(256) void convlstm_step_kernel(
    const float* __restrict__ xn_t,
    const float* __restrict__ h_in1, float* __restrict__ h_out1, float* __restrict__ c1,
    const float* __restrict__ w1, const float* __restrict__ b1,
    const float* __restrict__ h_in2, float* __restrict__ h_out2, float* __restrict__ c2,
    const float* __restrict__ w2, const float* __restrict__ b2)
{
    const int branch = blockIdx.y;
    const int dil = 1 + branch;
    const float* h_in  = branch ? h_in2  : h_in1;
    float*       h_out = branch ? h_out2 : h_out1;
    float*       cbuf  = branch ? c2     : c1;
    const float* w     = branch ? w2     : w1;
    const float* bias  = branch ? b2     : b1;

    const int b  = blockIdx.x >> 6;
    const int oc = blockIdx.x & 63;

    __shared__ float4 wl[801];   // 89 cin * 9 taps, 4 gates each = 12.8 KB
    for (int i = threadIdx.x; i < 3204; i += 256) {
        int g = i & 3, rk = i >> 2;                  // rk = cin*9 + k9
        ((float*)wl)[i] = w[(size_t)(g * 64 + oc) * 801 + rk];
    }
    __syncthreads();

    const float* xb = xn_t + (size_t)b * IND_ * NPIX;
    const float* hb = h_in + (size_t)b * HID_ * NPIX;
    const float bi = bias[oc], bf = bias[64 + oc], bo = bias[128 + oc], bg = bias[192 + oc];

    for (int p = threadIdx.x; p < NPIX; p += 256) {
        const int y = p / 25, x = p % 25;
        float ai = bi, af = bf, ao = bo, ag = bg;
        for (int ky = 0; ky < 3; ++ky) {
            const int iy = y + (ky - 1) * dil;
            if (iy < 0 || iy >= 25) continue;
            for (int kx = 0; kx < 3; ++kx) {
                const int ix = x + (kx - 1) * dil;
                if (ix < 0 || ix >= 25) continue;
                const int off = iy * 25 + ix;
                const int k9  = ky * 3 + kx;
                const float*  xp = xb + off;
                const float4* wp = wl + k9;
#pragma unroll
                for (int c = 0; c < IND_; ++c) {
                    const float  v  = xp[c * NPIX];
                    const float4 wv = wp[c * 9];
                    ai += v * wv.x; af += v * wv.y; ao += v * wv.z; ag += v * wv.w;
                }
                const float*  hp  = hb + off;
                const float4* wph = wl + (IND_ * 9 + k9);
#pragma unroll 8
                for (int c = 0; c < HID_; ++c) {
                    const float  v  = hp[c * NPIX];
                    const float4 wv = wph[c * 9];
                    ai += v * wv.x; af += v * wv.y; ao += v * wv.z; ag += v * wv.w;
                }
            }
        }
        const size_t idx = ((size_t)(b * 64 + oc)) * NPIX + p;
        const float cold = cbuf[idx];
        const float cn = sigmoidf_(af) * cold + sigmoidf_(ai) * tanh_fast(ag);
        const float hn = sigmoidf_(ao) * tanh_fast(cn);
        cbuf[idx]  = cn;
        h_out[idx] = hn;
    }
}

// Final 3x3 conv (128 -> 64, pad 1) + bias + ReLU + 2x2/2 maxpool, fused.
// One block per (b, oc); thread t < 144 computes pooled pixel (py,px).
__global__ __launch_bounds__(192) void conv_pool_kernel(
    const float* __restrict__ h1, const float* __restrict__ h2,
    const float* __restrict__ wc, const float* __restrict__ bc,
    float* __restrict__ pool)
{
    const int b  = blockIdx.x >> 6;
    const int oc = blockIdx.x & 63;
    __shared__ float wl[1152];   // 128 cin * 9
    for (int i = threadIdx.x; i < 1152; i += 192) wl[i] = wc[(size_t)oc * 1152 + i];
    __syncthreads();
    if (threadIdx.x >= 144) return;
    const int py = threadIdx.x / 12, px = threadIdx.x % 12;
    const float bias = bc[oc];
    const float* p1b = h1 + (size_t)(b * 64) * NPIX;
    const float* p2b = h2 + (size_t)(b * 64) * NPIX;
    float mx = -INFINITY;
    for (int sy = 0; sy < 2; ++sy) {
        for (int sx = 0; sx < 2; ++sx) {
            const int cy = 2 * py + sy, cx = 2 * px + sx;
            float acc = bias;
            for (int ky = 0; ky < 3; ++ky) {
                const int iy = cy - 1 + ky;
                if (iy < 0 || iy >= 25) continue;
                for (int kx = 0; kx < 3; ++kx) {
                    const int ix = cx - 1 + kx;
                    if (ix < 0 || ix >= 25) continue;
                    const int off = iy * 25 + ix;
                    const int k9  = ky * 3 + kx;
#pragma unroll 8
                    for (int c = 0; c < 64; ++c) acc += p1b[c * NPIX + off] * wl[c * 9 + k9];
#pragma unroll 8
                    for (int c = 0; c < 64; ++c) acc += p2b[c * NPIX + off] * wl[(64 + c) * 9 + k9];
                }
            }
            acc = fmaxf(acc, 0.f);
            mx = fmaxf(mx, acc);
        }
    }
    // torch-style flatten of (B, 64, 12, 12): index = oc*144 + py*12 + px
    pool[(size_t)b * 9216 + oc * 144 + py * 12 + px] = mx;
}

// FC head: fc1(9216->64)+ReLU, fc2(64->32)+ReLU, fc3(32->2), log_softmax. One block per b.
__global__ __launch_bounds__(256) void head_kernel(
    const float* __restrict__ pool,
    const float* __restrict__ w1, const float* __restrict__ b1,
    const float* __restrict__ w2, const float* __restrict__ b2,
    const float* __restrict__ w3, const float* __restrict__ b3,
    float* __restrict__ out)
{
    const int b = blockIdx.x;
    __shared__ float pl[9216];
    __shared__ float f1[64];
    __shared__ float f2[32];
    for (int i = threadIdx.x; i < 9216; i += 256) pl[i] = pool[(size_t)b * 9216 + i];
    __syncthreads();
    const int tid = threadIdx.x;
    if (tid < 64) {
        float acc = b1[tid];
        const float* wr = w1 + (size_t)tid * 9216;
        for (int k = 0; k < 9216; ++k) acc += pl[k] * wr[k];
        f1[tid] = fmaxf(acc, 0.f);
    }
    __syncthreads();
    if (tid < 32) {
        float acc = b2[tid];
        const float* wr = w2 + (size_t)tid * 64;
#pragma unroll
        for (int k = 0; k < 64; ++k) acc += f1[k] * wr[k];
        f2[tid] = fmaxf(acc, 0.f);
    }
    __syncthreads();
    if (tid == 0) {
        float y0 = b3[0], y1 = b3[1];
#pragma unroll
        for (int k = 0; k < 32; ++k) { y0 += f2[k] * w3[k]; y1 += f2[k] * w3[32 + k]; }
        const float m = fmaxf(y0, y1);
        const float lse = m + logf(expf(y0 - m) + expf(y1 - m));
        out[b * 2 + 0] = y0 - lse;
        out[b * 2 + 1] = y1 - lse;
    }
}

extern "C" void kernel_launch(void* const* d_in, const int* in_sizes, int n_in,
                              void* d_out, int out_size, void* d_ws, size_t ws_size,
                              hipStream_t stream) {
    const float* x    = (const float*)d_in[0];
    const float* ln_g = (const float*)d_in[1];
    const float* ln_b = (const float*)d_in[2];
    const float* w_l1 = (const float*)d_in[3];
    const float* b_l1 = (const float*)d_in[4];
    const float* w_l2 = (const float*)d_in[5];
    const float* b_l2 = (const float*)d_in[6];
    const float* w_c  = (const float*)d_in[7];
    const float* b_c  = (const float*)d_in[8];
    const float* w_f1 = (const float*)d_in[9];
    const float* b_f1 = (const float*)d_in[10];
    const float* w_f2 = (const float*)d_in[11];
    const float* b_f2 = (const float*)d_in[12];
    const float* w_f3 = (const float*)d_in[13];
    const float* b_f3 = (const float*)d_in[14];

    float* ws = (float*)d_ws;
    // Workspace layout (floats). Zero region [h1a..c2) is contiguous: 4 * 2,560,000.
    float* xn_t = ws;                    //  1,000,000  (B,25,25,25)
    float* h1a  = ws + 1000000;          //  2,560,000  (B,64,25,25)
    float* c1   = ws + 3560000;          //  2,560,000
    float* h2a  = ws + 6120000;          //  2,560,000
    float* c2   = ws + 8680000;          //  2,560,000
    float* h1b  = ws + 11240000;         //  2,560,000
    float* h2b  = ws + 13800000;         //  2,560,000
    float* pool = ws + 16360000;         //    589,824  (B, 9216)
    // total = 16,949,824 floats ≈ 64.7 MiB

    // zero-init h0 and c0 for both branches (ws is poisoned, not re-poisoned between replays)
    fill_zero_kernel<<<(10240000 + 255) / 256, 256, 0, stream>>>(h1a, 10240000);

    float* hin1 = h1a; float* hout1 = h1b;
    float* hin2 = h2a; float* hout2 = h2b;
    for (int t = 0; t < T_; ++t) {
        ln_t_kernel<<<(B_ * NPIX + 255) / 256, 256, 0, stream>>>(x, xn_t, ln_g, ln_b, t);
        convlstm_step_kernel<<<dim3(B_ * 64, 2), 256, 0, stream>>>(
            xn_t,
            hin1, hout1, c1, w_l1, b_l1,
            hin2, hout2, c2, w_l2, b_l2);
        float* tmp;
        tmp = hin1; hin1 = hout1; hout1 = tmp;
        tmp = hin2; hin2 = hout2; hout2 = tmp;
    }
    // final hidden states are in hin1 / hin2 after the last swap
    conv_pool_kernel<<<B_ * 64, 192, 0, stream>>>(hin1, hin2, w_c, b_c, pool);
    head_kernel<<<B_, 256, 0, stream>>>(pool, w_f1, b_f1, w_f2, b_f2, w_f3, b_f3, (float*)d_out);
}

// Round 2
// 5264.592 us; speedup vs baseline: 35.0894x; 35.0894x over previous
//
#include <hip/hip_runtime.h>
#include <hip/hip_bf16.h>
#include <math.h>

#define B_    64
#define T_    24
#define IND_  25
#define HID_  64
#define NPIX  625   // 25*25

#define KPAD   96
#define UROWS0 736   // branch 0: d=1, Wp=27, 27*27=729 (+margin for garbage-col tap reads)
#define UROWS1 856   // branch 1: d=2, Wp=29, 29*29=841 (+margin)
#define UB0    (UROWS0*KPAD)          // 70656 elems per batch
#define UB1    (UROWS1*KPAD)          // 82176
#define USZ0   (B_*UB0)               // 4,521,984
#define USZ1   (B_*UB1)               // 5,259,264
#define UTOT   (2*USZ0 + 2*USZ1)      // 19,562,496 ushorts = 39,124,992 B

typedef __bf16 bf16x8 __attribute__((ext_vector_type(8)));
typedef float  f32x4  __attribute__((ext_vector_type(4)));
typedef unsigned short ushort_t;
typedef unsigned int   uint_t;

__device__ __forceinline__ float sigmoidf_(float x) { return 1.f / (1.f + __expf(-x)); }
__device__ __forceinline__ float tanh_fast(float x) { return 2.f / (1.f + __expf(-2.f * x)) - 1.f; }
__device__ __forceinline__ ushort_t f2bf(float f) {
    unsigned int u = __float_as_uint(f);
    u += 0x7FFFu + ((u >> 16) & 1u);        // round-to-nearest-even
    return (ushort_t)(u >> 16);
}
__device__ __forceinline__ float bf2f(ushort_t h) {
    return __uint_as_float(((unsigned int)h) << 16);
}

__global__ __launch_bounds__(256) void fill_zero_kernel(uint_t* __restrict__ p, int n) {
    int i = blockIdx.x * 256 + threadIdx.x;
    if (i < n) p[i] = 0u;
}

// Repack ConvLSTM weights: src [gate*64+oc][c=89][ky][kx] fp32 ->
// Wpk[br][tap][m'=oc*4+gate][k=96] bf16 (k>=89 zero).
__global__ __launch_bounds__(256) void repack_w_kernel(
    const float* __restrict__ w1, const float* __restrict__ w2, ushort_t* __restrict__ Wpk)
{
    int id = blockIdx.x * 256 + threadIdx.x;
    if (id >= 2 * 9 * 256 * KPAD) return;
    int k   = id % KPAD;
    int m   = (id / KPAD) % 256;
    int tap = (id / (KPAD * 256)) % 9;
    int br  = id / (KPAD * 256 * 9);
    int oc = m >> 2, gate = m & 3;
    const float* w = br ? w2 : w1;
    float v = (k < IND_ + HID_) ? w[((size_t)(gate * 64 + oc) * 89 + k) * 9 + tap] : 0.f;
    Wpk[id] = f2bf(v);
}

// LayerNorm for timestep t, writing bf16 directly into both branches' current U buffers
// (transposed layout U[b][padded_row][k], k 0..24).
__global__ __launch_bounds__(256) void ln_t_kernel(
    const float* __restrict__ x, const float* __restrict__ gamma, const float* __restrict__ beta,
    ushort_t* __restrict__ U0, ushort_t* __restrict__ U1, int t)
{
    int p = blockIdx.x * 256 + threadIdx.x;
    if (p >= B_ * NPIX) return;
    int b = p / NPIX, hw = p % NPIX;
    int y = hw / 25, xx = hw % 25;
    const float* xp = x + ((size_t)(b * T_ + t) * IND_) * NPIX + hw;
    float v[IND_];
    float s = 0.f;
#pragma unroll
    for (int c = 0; c < IND_; ++c) { v[c] = xp[c * NPIX]; s += v[c]; }
    float mu = s * (1.f / IND_);
    float ss = 0.f;
#pragma unroll
    for (int c = 0; c < IND_; ++c) { float d = v[c] - mu; ss += d * d; }
    float rstd = rsqrtf(ss * (1.f / IND_) + 1e-5f);
    ushort_t* o0 = U0 + (size_t)b * UB0 + (size_t)((y + 1) * 27 + (xx + 1)) * KPAD;
    ushort_t* o1 = U1 + (size_t)b * UB1 + (size_t)((y + 2) * 29 + (xx + 2)) * KPAD;
#pragma unroll
    for (int c = 0; c < IND_; ++c) {
        ushort_t hv = f2bf((v[c] - mu) * rstd * gamma[c] + beta[c]);
        o0[c] = hv;
        o1[c] = hv;
    }
}

// One ConvLSTM timestep, both branches, as implicit-GEMM MFMA.
// Grid: (rowgroup 5, batch 64, branch 2). 512 threads = 8 waves (4M x 2N).
// M=256 (oc*4+gate interleave), N=160 (5 rows x 32 padded cols), K=9 taps x 96.
__global__ __launch_bounds__(512) void convlstm_mfma_kernel(
    const ushort_t* __restrict__ U0c, const ushort_t* __restrict__ U1c,
    ushort_t* __restrict__ U0n, ushort_t* __restrict__ U1n,
    const ushort_t* __restrict__ Wpk,
    const float* __restrict__ bias1, const float* __restrict__ bias2,
    float* __restrict__ cst)
{
    const int rg = blockIdx.x;
    const int b  = blockIdx.y;
    const int br = blockIdx.z;
    const int d  = 1 + br;
    const int Wp = 25 + 2 * d;
    const ushort_t* __restrict__ Ucur = br ? (U1c + (size_t)b * UB1) : (U0c + (size_t)b * UB0);
    ushort_t* __restrict__ Unxt       = br ? (U1n + (size_t)b * UB1) : (U0n + (size_t)b * UB0);
    const float* __restrict__ bias = br ? bias2 : bias1;
    const ushort_t* __restrict__ Wb = Wpk + (size_t)br * (9 * 256 * KPAD);

    const int tid  = threadIdx.x;
    const int w    = tid >> 6, lane = tid & 63;
    const int wm   = w & 3, wn = w >> 2;
    const int l16  = lane & 15, kh = lane >> 4;
    const int koff = kh * 8;

    f32x4 acc[4][5];
#pragma unroll
    for (int i = 0; i < 4; ++i)
#pragma unroll
        for (int j = 0; j < 5; ++j) acc[i][j] = (f32x4){0.f, 0.f, 0.f, 0.f};

    int baserow[5];
#pragma unroll
    for (int nf = 0; nf < 5; ++nf) {
        int n = wn * 80 + nf * 16 + l16;
        baserow[nf] = (rg * 5 + (n >> 5)) * Wp + (n & 31);
    }

    const ushort_t* __restrict__ Wm = Wb + (size_t)(wm * 64 + l16) * KPAD + koff;

    for (int tap = 0; tap < 9; ++tap) {
        const int ky = tap / 3, kx = tap - 3 * ky;
        const int toff = (ky * Wp + kx) * d;
        const ushort_t* __restrict__ Wt = Wm + (size_t)tap * (256 * KPAD);
        const ushort_t* Urow[5];
#pragma unroll
        for (int nf = 0; nf < 5; ++nf)
            Urow[nf] = Ucur + (size_t)(baserow[nf] + toff) * KPAD + koff;
#pragma unroll
        for (int kk = 0; kk < 3; ++kk) {
            bf16x8 af[4], bfr[5];
#pragma unroll
            for (int mf = 0; mf < 4; ++mf)
                af[mf] = *(const bf16x8*)(Wt + mf * 16 * KPAD + kk * 32);
#pragma unroll
            for (int nf = 0; nf < 5; ++nf)
                bfr[nf] = *(const bf16x8*)(Urow[nf] + kk * 32);
#pragma unroll
            for (int mf = 0; mf < 4; ++mf)
#pragma unroll
                for (int nf = 0; nf < 5; ++nf)
                    acc[mf][nf] = __builtin_amdgcn_mfma_f32_16x16x32_bf16(
                        af[mf], bfr[nf], acc[mf][nf], 0, 0, 0);
        }
    }

    // Epilogue: fused bias + gates + state update. C/D layout (m89-verified):
    // col = lane&15 (pixel), row = (lane>>4)*4 + reg -> reg IS the gate (m' = oc*4+gate).
#pragma unroll
    for (int mf = 0; mf < 4; ++mf) {
        const int oc = wm * 16 + mf * 4 + kh;
        const float bi = bias[oc], bff = bias[64 + oc], bo = bias[128 + oc], bg = bias[192 + oc];
#pragma unroll
        for (int nf = 0; nf < 5; ++nf) {
            const int n = wn * 80 + nf * 16 + l16;
            const int xx = n & 31;
            if (xx >= 25) continue;
            const int y = rg * 5 + (n >> 5);
            const int pix = y * 25 + xx;
            const size_t ci = ((size_t)((br * B_ + b) * HID_ + oc)) * NPIX + pix;
            const float zi = acc[mf][nf][0] + bi;
            const float zf = acc[mf][nf][1] + bff;
            const float zo = acc[mf][nf][2] + bo;
            const float zg = acc[mf][nf][3] + bg;
            const float co = cst[ci];
            const float cn = sigmoidf_(zf) * co + sigmoidf_(zi) * tanh_fast(zg);
            const float hn = sigmoidf_(zo) * tanh_fast(cn);
            cst[ci] = cn;
            Unxt[(size_t)((y + d) * Wp + (xx + d)) * KPAD + IND_ + oc] = f2bf(hn);
        }
    }
}

// Extract final hidden states from U buffers (bf16, transposed) to fp32 planar [br][b][ch][pix].
__global__ __launch_bounds__(256) void extract_h_kernel(
    const ushort_t* __restrict__ U0, const ushort_t* __restrict__ U1, float* __restrict__ h)
{
    int id = blockIdx.x * 256 + threadIdx.x;
    if (id >= 2 * B_ * HID_ * NPIX) return;
    int pix = id % NPIX;
    int ch  = (id / NPIX) % HID_;
    int b   = (id / (NPIX * HID_)) % B_;
    int br  = id / (NPIX * HID_ * B_);
    int y = pix / 25, xx = pix % 25;
    int dd = 1 + br, Wpp = 25 + 2 * dd;
    const ushort_t* U = br ? (U1 + (size_t)b * UB1) : (U0 + (size_t)b * UB0);
    h[id] = bf2f(U[(size_t)((y + dd) * Wpp + (xx + dd)) * KPAD + IND_ + ch]);
}

// Final 3x3 conv (128 -> 64, pad 1) + bias + ReLU + 2x2/2 maxpool, fused (proven in R1).
__global__ __launch_bounds__(192) void conv_pool_kernel(
    const float* __restrict__ h1, const float* __restrict__ h2,
    const float* __restrict__ wc, const float* __restrict__ bc,
    float* __restrict__ pool)
{
    const int b  = blockIdx.x >> 6;
    const int oc = blockIdx.x & 63;
    __shared__ float wl[1152];
    for (int i = threadIdx.x; i < 1152; i += 192) wl[i] = wc[(size_t)oc * 1152 + i];
    __syncthreads();
    if (threadIdx.x >= 144) return;
    const int py = threadIdx.x / 12, px = threadIdx.x % 12;
    const float bias = bc[oc];
    const float* p1b = h1 + (size_t)(b * 64) * NPIX;
    const float* p2b = h2 + (size_t)(b * 64) * NPIX;
    float mx = -INFINITY;
    for (int sy = 0; sy < 2; ++sy) {
        for (int sx = 0; sx < 2; ++sx) {
            const int cy = 2 * py + sy, cx = 2 * px + sx;
            float acc = bias;
            for (int ky = 0; ky < 3; ++ky) {
                const int iy = cy - 1 + ky;
                if (iy < 0 || iy >= 25) continue;
                for (int kx = 0; kx < 3; ++kx) {
                    const int ix = cx - 1 + kx;
                    if (ix < 0 || ix >= 25) continue;
                    const int off = iy * 25 + ix;
                    const int k9  = ky * 3 + kx;
#pragma unroll 8
                    for (int c = 0; c < 64; ++c) acc += p1b[c * NPIX + off] * wl[c * 9 + k9];
#pragma unroll 8
                    for (int c = 0; c < 64; ++c) acc += p2b[c * NPIX + off] * wl[(64 + c) * 9 + k9];
                }
            }
            acc = fmaxf(acc, 0.f);
            mx = fmaxf(mx, acc);
        }
    }
    pool[(size_t)b * 9216 + oc * 144 + py * 12 + px] = mx;
}

// FC head (proven in R1).
__global__ __launch_bounds__(256) void head_kernel(
    const float* __restrict__ pool,
    const float* __restrict__ w1, const float* __restrict__ b1,
    const float* __restrict__ w2, const float* __restrict__ b2,
    const float* __restrict__ w3, const float* __restrict__ b3,
    float* __restrict__ out)
{
    const int b = blockIdx.x;
    __shared__ float pl[9216];
    __shared__ float f1[64];
    __shared__ float f2[32];
    for (int i = threadIdx.x; i < 9216; i += 256) pl[i] = pool[(size_t)b * 9216 + i];
    __syncthreads();
    const int tid = threadIdx.x;
    if (tid < 64) {
        float acc = b1[tid];
        const float* wr = w1 + (size_t)tid * 9216;
        for (int k = 0; k < 9216; ++k) acc += pl[k] * wr[k];
        f1[tid] = fmaxf(acc, 0.f);
    }
    __syncthreads();
    if (tid < 32) {
        float acc = b2[tid];
        const float* wr = w2 + (size_t)tid * 64;
#pragma unroll
        for (int k = 0; k < 64; ++k) acc += f1[k] * wr[k];
        f2[tid] = fmaxf(acc, 0.f);
    }
    __syncthreads();
    if (tid == 0) {
        float y0 = b3[0], y1 = b3[1];
#pragma unroll
        for (int k = 0; k < 32; ++k) { y0 += f2[k] * w3[k]; y1 += f2[k] * w3[32 + k]; }
        const float m = fmaxf(y0, y1);
        const float lse = m + logf(expf(y0 - m) + expf(y1 - m));
        out[b * 2 + 0] = y0 - lse;
        out[b * 2 + 1] = y1 - lse;
    }
}

extern "C" void kernel_launch(void* const* d_in, const int* in_sizes, int n_in,
                              void* d_out, int out_size, void* d_ws, size_t ws_size,
                              hipStream_t stream) {
    const float* x    = (const float*)d_in[0];
    const float* ln_g = (const float*)d_in[1];
    const float* ln_b = (const float*)d_in[2];
    const float* w_l1 = (const float*)d_in[3];
    const float* b_l1 = (const float*)d_in[4];
    const float* w_l2 = (const float*)d_in[5];
    const float* b_l2 = (const float*)d_in[6];
    const float* w_c  = (const float*)d_in[7];
    const float* b_c  = (const float*)d_in[8];
    const float* w_f1 = (const float*)d_in[9];
    const float* b_f1 = (const float*)d_in[10];
    const float* w_f2 = (const float*)d_in[11];
    const float* b_f2 = (const float*)d_in[12];
    const float* w_f3 = (const float*)d_in[13];
    const float* b_f3 = (const float*)d_in[14];

    // Workspace layout:
    //   [0 .. 39,124,992B)   U buffers (bf16): br0 bufA, br0 bufB, br1 bufA, br1 bufB
    //   [.. +20,480,000B)    c state fp32 [2][64][64][625]  (aliased later: h1,h2 fp32)
    //   [.. +884,736B)       repacked weights bf16 [2][9][256][96]
    //   pool fp32 (2.36MB) aliases the (dead) U region at offset 0.
    // Total ~60.5 MB.
    ushort_t* wsu = (ushort_t*)d_ws;
    float*    wsf = (float*)d_ws;
    uint_t*   wsi = (uint_t*)d_ws;

    ushort_t* U0A = wsu;
    ushort_t* U0B = wsu + USZ0;
    ushort_t* U1A = wsu + 2 * (size_t)USZ0;
    ushort_t* U1B = wsu + 2 * (size_t)USZ0 + USZ1;
    float*    cst = wsf + (UTOT / 2);                 // 5,120,000 floats
    ushort_t* Wpk = wsu + UTOT + 10240000;            // 442,368 bf16
    float*    hbuf = cst;                             // alias (c dead after last step)
    float*    pool = wsf;                             // alias (U dead after extract)

    // zero U buffers + c state every launch (graph replay leaves stale h/c otherwise)
    const int n_fill = (int)((UTOT * 2 + 20480000) / 4);   // 14,901,248 uints
    fill_zero_kernel<<<(n_fill + 255) / 256, 256, 0, stream>>>(wsi, n_fill);
    repack_w_kernel<<<(2 * 9 * 256 * KPAD + 255) / 256, 256, 0, stream>>>(w_l1, w_l2, Wpk);

    ushort_t* B0[2] = {U0A, U0B};
    ushort_t* B1[2] = {U1A, U1B};
    for (int t = 0; t < T_; ++t) {
        const int cur = t & 1, nxt = cur ^ 1;
        ln_t_kernel<<<(B_ * NPIX + 255) / 256, 256, 0, stream>>>(x, ln_g, ln_b, B0[cur], B1[cur], t);
        convlstm_mfma_kernel<<<dim3(5, B_, 2), 512, 0, stream>>>(
            B0[cur], B1[cur], B0[nxt], B1[nxt], Wpk, b_l1, b_l2, cst);
    }
    // final h is in buffer parity 0 (T=24 even)
    extract_h_kernel<<<(2 * B_ * HID_ * NPIX + 255) / 256, 256, 0, stream>>>(U0A, U1A, hbuf);
    conv_pool_kernel<<<B_ * 64, 192, 0, stream>>>(hbuf, hbuf + 2560000, w_c, b_c, pool);
    head_kernel<<<B_, 256, 0, stream>>>(pool, w_f1, b_f1, w_f2, b_f2, w_f3, b_f3, (float*)d_out);
}

// Round 3
// 3171.425 us; speedup vs baseline: 58.2487x; 1.6600x over previous
//
#include <hip/hip_runtime.h>
#include <hip/hip_bf16.h>
#include <math.h>

#define B_    64
#define T_    24
#define IND_  25
#define HID_  64
#define NPIX  625   // 25*25

#define KPAD   96
#define UROWS0 736   // branch 0: d=1, Wp=27, 27*27=729 (+margin for garbage-col tap reads)
#define UROWS1 856   // branch 1: d=2, Wp=29, 29*29=841 (+margin)
#define UB0    (UROWS0*KPAD)          // 70656 elems per batch
#define UB1    (UROWS1*KPAD)          // 82176
#define USZ0   (B_*UB0)               // 4,521,984
#define USZ1   (B_*UB1)               // 5,259,264
#define UTOT   (2*USZ0 + 2*USZ1)      // 19,562,496 ushorts = 39,124,992 B

// final-conv combined input: [b][832 padded rows(27x27 + guard)][K=128] bf16
#define HCROWS 832
#define HCB    (HCROWS*128)           // 106,496 per batch
#define HCTOT  (B_*HCB)               // 6,815,744 ushorts = 13.6 MB

typedef __bf16 bf16x8 __attribute__((ext_vector_type(8)));
typedef float  f32x4  __attribute__((ext_vector_type(4)));
typedef unsigned short ushort_t;
typedef unsigned int   uint_t;

__device__ __forceinline__ float sigmoidf_(float x) { return 1.f / (1.f + __expf(-x)); }
__device__ __forceinline__ float tanh_fast(float x) { return 2.f / (1.f + __expf(-2.f * x)) - 1.f; }
__device__ __forceinline__ ushort_t f2bf(float f) {
    unsigned int u = __float_as_uint(f);
    u += 0x7FFFu + ((u >> 16) & 1u);        // round-to-nearest-even
    return (ushort_t)(u >> 16);
}
__device__ __forceinline__ float bf2f(ushort_t h) {
    return __uint_as_float(((unsigned int)h) << 16);
}

__global__ __launch_bounds__(256) void fill_zero_kernel(uint_t* __restrict__ p, int n) {
    int i = blockIdx.x * 256 + threadIdx.x;
    if (i < n) p[i] = 0u;
}

// Repack ConvLSTM weights: src [gate*64+oc][c=89][ky][kx] fp32 ->
// Wpk[br][tap][m'=oc*4+gate][k=96] bf16 (k>=89 zero).
__global__ __launch_bounds__(256) void repack_w_kernel(
    const float* __restrict__ w1, const float* __restrict__ w2, ushort_t* __restrict__ Wpk)
{
    int id = blockIdx.x * 256 + threadIdx.x;
    if (id >= 2 * 9 * 256 * KPAD) return;
    int k   = id % KPAD;
    int m   = (id / KPAD) % 256;
    int tap = (id / (KPAD * 256)) % 9;
    int br  = id / (KPAD * 256 * 9);
    int oc = m >> 2, gate = m & 3;
    const float* w = br ? w2 : w1;
    float v = (k < IND_ + HID_) ? w[((size_t)(gate * 64 + oc) * 89 + k) * 9 + tap] : 0.f;
    Wpk[id] = f2bf(v);
}

// Repack final conv weights: src [oc=64][cin=128][ky][kx] fp32 -> Wc[tap][oc][k=128] bf16.
__global__ __launch_bounds__(256) void repack_wc_kernel(
    const float* __restrict__ wc, ushort_t* __restrict__ Wc)
{
    int id = blockIdx.x * 256 + threadIdx.x;
    if (id >= 9 * 64 * 128) return;
    int k   = id % 128;
    int oc  = (id / 128) % 64;
    int tap = id / (128 * 64);
    Wc[id] = f2bf(wc[((size_t)(oc * 128) + k) * 9 + tap]);
}

// LayerNorm for timestep t, writing bf16 directly into both branches' current U buffers
// (transposed layout U[b][padded_row][k], k 0..24).
__global__ __launch_bounds__(256) void ln_t_kernel(
    const float* __restrict__ x, const float* __restrict__ gamma, const float* __restrict__ beta,
    ushort_t* __restrict__ U0, ushort_t* __restrict__ U1, int t)
{
    int p = blockIdx.x * 256 + threadIdx.x;
    if (p >= B_ * NPIX) return;
    int b = p / NPIX, hw = p % NPIX;
    int y = hw / 25, xx = hw % 25;
    const float* xp = x + ((size_t)(b * T_ + t) * IND_) * NPIX + hw;
    float v[IND_];
    float s = 0.f;
#pragma unroll
    for (int c = 0; c < IND_; ++c) { v[c] = xp[c * NPIX]; s += v[c]; }
    float mu = s * (1.f / IND_);
    float ss = 0.f;
#pragma unroll
    for (int c = 0; c < IND_; ++c) { float d = v[c] - mu; ss += d * d; }
    float rstd = rsqrtf(ss * (1.f / IND_) + 1e-5f);
    ushort_t* o0 = U0 + (size_t)b * UB0 + (size_t)((y + 1) * 27 + (xx + 1)) * KPAD;
    ushort_t* o1 = U1 + (size_t)b * UB1 + (size_t)((y + 2) * 29 + (xx + 2)) * KPAD;
#pragma unroll
    for (int c = 0; c < IND_; ++c) {
        ushort_t hv = f2bf((v[c] - mu) * rstd * gamma[c] + beta[c]);
        o0[c] = hv;
        o1[c] = hv;
    }
}

// One ConvLSTM timestep, both branches, as implicit-GEMM MFMA.
// Grid: (rowgroup 5, batch 64, branch 2). 512 threads = 8 waves (4M x 2N).
// M=256 (oc*4+gate interleave), N=160 (5 rows x 32 padded cols), K=9 taps x 96.
__global__ __launch_bounds__(512) void convlstm_mfma_kernel(
    const ushort_t* __restrict__ U0c, const ushort_t* __restrict__ U1c,
    ushort_t* __restrict__ U0n, ushort_t* __restrict__ U1n,
    const ushort_t* __restrict__ Wpk,
    const float* __restrict__ bias1, const float* __restrict__ bias2,
    float* __restrict__ cst)
{
    const int rg = blockIdx.x;
    const int b  = blockIdx.y;
    const int br = blockIdx.z;
    const int d  = 1 + br;
    const int Wp = 25 + 2 * d;
    const ushort_t* __restrict__ Ucur = br ? (U1c + (size_t)b * UB1) : (U0c + (size_t)b * UB0);
    ushort_t* __restrict__ Unxt       = br ? (U1n + (size_t)b * UB1) : (U0n + (size_t)b * UB0);
    const float* __restrict__ bias = br ? bias2 : bias1;
    const ushort_t* __restrict__ Wb = Wpk + (size_t)br * (9 * 256 * KPAD);

    const int tid  = threadIdx.x;
    const int w    = tid >> 6, lane = tid & 63;
    const int wm   = w & 3, wn = w >> 2;
    const int l16  = lane & 15, kh = lane >> 4;
    const int koff = kh * 8;

    f32x4 acc[4][5];
#pragma unroll
    for (int i = 0; i < 4; ++i)
#pragma unroll
        for (int j = 0; j < 5; ++j) acc[i][j] = (f32x4){0.f, 0.f, 0.f, 0.f};

    int baserow[5];
#pragma unroll
    for (int nf = 0; nf < 5; ++nf) {
        int n = wn * 80 + nf * 16 + l16;
        baserow[nf] = (rg * 5 + (n >> 5)) * Wp + (n & 31);
    }

    const ushort_t* __restrict__ Wm = Wb + (size_t)(wm * 64 + l16) * KPAD + koff;

    for (int tap = 0; tap < 9; ++tap) {
        const int ky = tap / 3, kx = tap - 3 * ky;
        const int toff = (ky * Wp + kx) * d;
        const ushort_t* __restrict__ Wt = Wm + (size_t)tap * (256 * KPAD);
        const ushort_t* Urow[5];
#pragma unroll
        for (int nf = 0; nf < 5; ++nf)
            Urow[nf] = Ucur + (size_t)(baserow[nf] + toff) * KPAD + koff;
#pragma unroll
        for (int kk = 0; kk < 3; ++kk) {
            bf16x8 af[4], bfr[5];
#pragma unroll
            for (int mf = 0; mf < 4; ++mf)
                af[mf] = *(const bf16x8*)(Wt + mf * 16 * KPAD + kk * 32);
#pragma unroll
            for (int nf = 0; nf < 5; ++nf)
                bfr[nf] = *(const bf16x8*)(Urow[nf] + kk * 32);
#pragma unroll
            for (int mf = 0; mf < 4; ++mf)
#pragma unroll
                for (int nf = 0; nf < 5; ++nf)
                    acc[mf][nf] = __builtin_amdgcn_mfma_f32_16x16x32_bf16(
                        af[mf], bfr[nf], acc[mf][nf], 0, 0, 0);
        }
    }

    // Epilogue: fused bias + gates + state update. C/D layout (m89-verified):
    // col = lane&15 (pixel), row = (lane>>4)*4 + reg -> reg IS the gate (m' = oc*4+gate).
#pragma unroll
    for (int mf = 0; mf < 4; ++mf) {
        const int oc = wm * 16 + mf * 4 + kh;
        const float bi = bias[oc], bff = bias[64 + oc], bo = bias[128 + oc], bg = bias[192 + oc];
#pragma unroll
        for (int nf = 0; nf < 5; ++nf) {
            const int n = wn * 80 + nf * 16 + l16;
            const int xx = n & 31;
            if (xx >= 25) continue;
            const int y = rg * 5 + (n >> 5);
            const int pix = y * 25 + xx;
            const size_t ci = ((size_t)((br * B_ + b) * HID_ + oc)) * NPIX + pix;
            const float zi = acc[mf][nf][0] + bi;
            const float zf = acc[mf][nf][1] + bff;
            const float zo = acc[mf][nf][2] + bo;
            const float zg = acc[mf][nf][3] + bg;
            const float co = cst[ci];
            const float cn = sigmoidf_(zf) * co + sigmoidf_(zi) * tanh_fast(zg);
            const float hn = sigmoidf_(zo) * tanh_fast(cn);
            cst[ci] = cn;
            Unxt[(size_t)((y + d) * Wp + (xx + d)) * KPAD + IND_ + oc] = f2bf(hn);
        }
    }
}

// Combine final hidden states of both branches into Hc[b][(y+1)*27+(x+1)][k=128] bf16
// (k 0..63 = h1, 64..127 = h2). Borders stay zero (region zeroed beforehand).
__global__ __launch_bounds__(256) void combine_h_kernel(
    const ushort_t* __restrict__ U0, const ushort_t* __restrict__ U1, ushort_t* __restrict__ Hc)
{
    int id = blockIdx.x * 256 + threadIdx.x;
    if (id >= B_ * NPIX * 128) return;
    int k   = id % 128;
    int pix = (id / 128) % NPIX;
    int b   = id / (128 * NPIX);
    int y = pix / 25, xx = pix % 25;
    ushort_t v;
    if (k < 64) v = U0[(size_t)b * UB0 + (size_t)((y + 1) * 27 + (xx + 1)) * KPAD + IND_ + k];
    else        v = U1[(size_t)b * UB1 + (size_t)((y + 2) * 29 + (xx + 2)) * KPAD + IND_ + (k - 64)];
    Hc[(size_t)b * HCB + (size_t)((y + 1) * 27 + (xx + 1)) * 128 + k] = v;
}

// Final 3x3 conv (128->64, pad 1) + bias + ReLU via MFMA implicit-GEMM.
// Grid (7 rowgroups x 64 b), 512 thr = 8 waves (2M x 4N). M=64, N=128 (4 rows x 32 cols),
// K = 9 taps x 128.
__global__ __launch_bounds__(512) void conv_mfma_kernel(
    const ushort_t* __restrict__ Hc, const ushort_t* __restrict__ Wc,
    const float* __restrict__ bc, float* __restrict__ conv_out)
{
    const int rg = blockIdx.x;
    const int b  = blockIdx.y;
    const ushort_t* __restrict__ Hb = Hc + (size_t)b * HCB;

    const int tid  = threadIdx.x;
    const int w    = tid >> 6, lane = tid & 63;
    const int wm   = w & 1, wn = w >> 1;
    const int l16  = lane & 15, kh = lane >> 4;
    const int koff = kh * 8;

    f32x4 acc[2][2];
#pragma unroll
    for (int i = 0; i < 2; ++i)
#pragma unroll
        for (int j = 0; j < 2; ++j) acc[i][j] = (f32x4){0.f, 0.f, 0.f, 0.f};

    int baserow[2];
#pragma unroll
    for (int nf = 0; nf < 2; ++nf) {
        int n = wn * 32 + nf * 16 + l16;
        baserow[nf] = (rg * 4 + (n >> 5)) * 27 + (n & 31);
    }
    const ushort_t* __restrict__ Wm = Wc + (size_t)(wm * 32 + l16) * 128 + koff;

    for (int tap = 0; tap < 9; ++tap) {
        const int ky = tap / 3, kx = tap - 3 * ky;
        const int toff = ky * 27 + kx;
        const ushort_t* __restrict__ Wt = Wm + (size_t)tap * (64 * 128);
        const ushort_t* Urow[2];
#pragma unroll
        for (int nf = 0; nf < 2; ++nf)
            Urow[nf] = Hb + (size_t)(baserow[nf] + toff) * 128 + koff;
#pragma unroll
        for (int kk = 0; kk < 4; ++kk) {
            bf16x8 af[2], bfr[2];
#pragma unroll
            for (int mf = 0; mf < 2; ++mf)
                af[mf] = *(const bf16x8*)(Wt + mf * 16 * 128 + kk * 32);
#pragma unroll
            for (int nf = 0; nf < 2; ++nf)
                bfr[nf] = *(const bf16x8*)(Urow[nf] + kk * 32);
#pragma unroll
            for (int mf = 0; mf < 2; ++mf)
#pragma unroll
                for (int nf = 0; nf < 2; ++nf)
                    acc[mf][nf] = __builtin_amdgcn_mfma_f32_16x16x32_bf16(
                        af[mf], bfr[nf], acc[mf][nf], 0, 0, 0);
        }
    }

#pragma unroll
    for (int mf = 0; mf < 2; ++mf) {
#pragma unroll
        for (int nf = 0; nf < 2; ++nf) {
            const int n = wn * 32 + nf * 16 + l16;
            const int xx = n & 31;
            if (xx >= 25) continue;
            const int y = rg * 4 + wn;
            if (y >= 25) continue;
#pragma unroll
            for (int r = 0; r < 4; ++r) {
                const int oc = wm * 32 + mf * 16 + kh * 4 + r;
                const float v = fmaxf(acc[mf][nf][r] + bc[oc], 0.f);
                conv_out[((size_t)(b * 64 + oc)) * NPIX + y * 25 + xx] = v;
            }
        }
    }
}

// 2x2/2 maxpool + torch-order flatten: pool[b][oc*144 + py*12 + px].
__global__ __launch_bounds__(256) void pool_kernel(
    const float* __restrict__ conv_out, float* __restrict__ pool)
{
    int id = blockIdx.x * 256 + threadIdx.x;
    if (id >= B_ * 64 * 144) return;
    int px = id % 12;
    int py = (id / 12) % 12;
    int oc = (id / 144) % 64;
    int b  = id / (144 * 64);
    const float* p = conv_out + ((size_t)(b * 64 + oc)) * NPIX;
    const int cy = 2 * py, cx = 2 * px;
    float mx = fmaxf(fmaxf(p[cy * 25 + cx], p[cy * 25 + cx + 1]),
                     fmaxf(p[(cy + 1) * 25 + cx], p[(cy + 1) * 25 + cx + 1]));
    pool[(size_t)b * 9216 + oc * 144 + py * 12 + px] = mx;
}

// FC head (proven in R1).
__global__ __launch_bounds__(256) void head_kernel(
    const float* __restrict__ pool,
    const float* __restrict__ w1, const float* __restrict__ b1,
    const float* __restrict__ w2, const float* __restrict__ b2,
    const float* __restrict__ w3, const float* __restrict__ b3,
    float* __restrict__ out)
{
    const int b = blockIdx.x;
    __shared__ float pl[9216];
    __shared__ float f1[64];
    __shared__ float f2[32];
    for (int i = threadIdx.x; i < 9216; i += 256) pl[i] = pool[(size_t)b * 9216 + i];
    __syncthreads();
    const int tid = threadIdx.x;
    if (tid < 64) {
        float acc = b1[tid];
        const float* wr = w1 + (size_t)tid * 9216;
        for (int k = 0; k < 9216; ++k) acc += pl[k] * wr[k];
        f1[tid] = fmaxf(acc, 0.f);
    }
    __syncthreads();
    if (tid < 32) {
        float acc = b2[tid];
        const float* wr = w2 + (size_t)tid * 64;
#pragma unroll
        for (int k = 0; k < 64; ++k) acc += f1[k] * wr[k];
        f2[tid] = fmaxf(acc, 0.f);
    }
    __syncthreads();
    if (tid == 0) {
        float y0 = b3[0], y1 = b3[1];
#pragma unroll
        for (int k = 0; k < 32; ++k) { y0 += f2[k] * w3[k]; y1 += f2[k] * w3[32 + k]; }
        const float m = fmaxf(y0, y1);
        const float lse = m + logf(expf(y0 - m) + expf(y1 - m));
        out[b * 2 + 0] = y0 - lse;
        out[b * 2 + 1] = y1 - lse;
    }
}

extern "C" void kernel_launch(void* const* d_in, const int* in_sizes, int n_in,
                              void* d_out, int out_size, void* d_ws, size_t ws_size,
                              hipStream_t stream) {
    const float* x    = (const float*)d_in[0];
    const float* ln_g = (const float*)d_in[1];
    const float* ln_b = (const float*)d_in[2];
    const float* w_l1 = (const float*)d_in[3];
    const float* b_l1 = (const float*)d_in[4];
    const float* w_l2 = (const float*)d_in[5];
    const float* b_l2 = (const float*)d_in[6];
    const float* w_c  = (const float*)d_in[7];
    const float* b_c  = (const float*)d_in[8];
    const float* w_f1 = (const float*)d_in[9];
    const float* b_f1 = (const float*)d_in[10];
    const float* w_f2 = (const float*)d_in[11];
    const float* b_f2 = (const float*)d_in[12];
    const float* w_f3 = (const float*)d_in[13];
    const float* b_f3 = (const float*)d_in[14];

    // Workspace (bytes):
    //   [0 .. 39.1MB)   U buffers bf16, laid out A,A,B,B: U0A, U1A, U0B, U1B.
    //                   After the loop the B half is dead -> Hc (13.6MB) aliases it.
    //   [39.1 .. 59.6MB) c state fp32 [2][64][64][625]; dead after loop ->
    //                   conv_out (10.2MB) + pool (2.4MB) alias it.
    //   [59.6 .. 60.5MB) Wpk (lstm weights bf16) ; then Wc (conv weights bf16, 147KB).
    // Total ~60.7 MB (< R1's proven 67.8 MB).
    ushort_t* wsu = (ushort_t*)d_ws;
    float*    wsf = (float*)d_ws;
    uint_t*   wsi = (uint_t*)d_ws;

    ushort_t* U0A = wsu;
    ushort_t* U1A = wsu + USZ0;
    ushort_t* U0B = wsu + USZ0 + USZ1;
    ushort_t* U1B = wsu + 2 * (size_t)USZ0 + USZ1;
    ushort_t* Hc  = U0B;                              // alias dead double-buffer half
    float*    cst = wsf + (UTOT / 2);                 // 5,120,000 floats
    float*    conv_out = cst;                         // alias (c dead after loop)
    float*    pool = cst + 2560000;
    ushort_t* Wpk = wsu + UTOT + 10240000;            // 442,368 bf16
    ushort_t* Wc  = Wpk + 2 * 9 * 256 * KPAD;         // 73,728 bf16

    // zero U buffers + c state every launch
    const int n_fill = (int)((UTOT * 2 + 20480000) / 4);
    fill_zero_kernel<<<(n_fill + 255) / 256, 256, 0, stream>>>(wsi, n_fill);
    repack_w_kernel<<<(2 * 9 * 256 * KPAD + 255) / 256, 256, 0, stream>>>(w_l1, w_l2, Wpk);
    repack_wc_kernel<<<(9 * 64 * 128 + 255) / 256, 256, 0, stream>>>(w_c, Wc);

    ushort_t* B0[2] = {U0A, U0B};
    ushort_t* B1[2] = {U1A, U1B};
    for (int t = 0; t < T_; ++t) {
        const int cur = t & 1, nxt = cur ^ 1;
        ln_t_kernel<<<(B_ * NPIX + 255) / 256, 256, 0, stream>>>(x, ln_g, ln_b, B0[cur], B1[cur], t);
        convlstm_mfma_kernel<<<dim3(5, B_, 2), 512, 0, stream>>>(
            B0[cur], B1[cur], B0[nxt], B1[nxt], Wpk, b_l1, b_l2, cst);
    }
    // final h is in parity-0 buffers (U0A/U1A). Rebuild Hc over the stale B half:
    fill_zero_kernel<<<(HCTOT / 2 + 255) / 256, 256, 0, stream>>>((uint_t*)Hc, HCTOT / 2);
    combine_h_kernel<<<(B_ * NPIX * 128 + 255) / 256, 256, 0, stream>>>(U0A, U1A, Hc);
    conv_mfma_kernel<<<dim3(7, B_), 512, 0, stream>>>(Hc, Wc, b_c, conv_out);
    pool_kernel<<<(B_ * 64 * 144 + 255) / 256, 256, 0, stream>>>(conv_out, pool);
    head_kernel<<<B_, 256, 0, stream>>>(pool, w_f1, b_f1, w_f2, b_f2, w_f3, b_f3, (float*)d_out);
}

// Round 4
// 2389.318 us; speedup vs baseline: 77.3156x; 1.3273x over previous
//
#include <hip/hip_runtime.h>
#include <hip/hip_bf16.h>
#include <math.h>

#define B_    64
#define T_    24
#define IND_  25
#define HID_  64
#define NPIX  625   // 25*25

#define KPAD   96
#define PADK   104   // LDS row stride (elems): 208B -> uniform 2-way banks on ds_read_b128
#define UROWS0 768   // branch 0: d=1, Wp=27; staging needs rg*135+223 <= 763
#define UROWS1 896   // branch 1: d=2, Wp=29; staging needs rg*145+295 <= 875
#define UB0    (UROWS0*KPAD)          // 73,728 elems per batch
#define UB1    (UROWS1*KPAD)          // 86,016
#define USZ0   (B_*UB0)               // 4,718,592
#define USZ1   (B_*UB1)               // 5,505,024
#define UTOT   (2*USZ0 + 2*USZ1)      // 20,447,232 ushorts = 40.9 MB

#define LDSROWS 295                   // max staged rows (br1); br0 uses 223
// final-conv combined input: [b][832 padded rows(27x27 + guard)][K=128] bf16
#define HCROWS 832
#define HCB    (HCROWS*128)
#define HCTOT  (B_*HCB)               // 6,815,744 ushorts

#define WFRAG_PER_BR (9*3*4*4*512)    // 221,184
#define WFRAG_TOT    (2*WFRAG_PER_BR) // 442,368

typedef __bf16 bf16x8 __attribute__((ext_vector_type(8)));
typedef float  f32x4  __attribute__((ext_vector_type(4)));
typedef unsigned short ushort_t;
typedef unsigned int   uint_t;

__device__ __forceinline__ float sigmoidf_(float x) { return 1.f / (1.f + __expf(-x)); }
__device__ __forceinline__ float tanh_fast(float x) { return 2.f / (1.f + __expf(-2.f * x)) - 1.f; }
__device__ __forceinline__ ushort_t f2bf(float f) {
    unsigned int u = __float_as_uint(f);
    u += 0x7FFFu + ((u >> 16) & 1u);
    return (ushort_t)(u >> 16);
}
__device__ __forceinline__ float bf2f(ushort_t h) {
    return __uint_as_float(((unsigned int)h) << 16);
}

__global__ __launch_bounds__(256) void fill_zero_kernel(uint_t* __restrict__ p, int n) {
    int i = blockIdx.x * 256 + threadIdx.x;
    if (i < n) p[i] = 0u;
}

// Repack ConvLSTM weights into FRAGMENT order so A-loads are lane-dense:
// Wfrag[br][tap][kk][wm][mf][lane][e], lane=(kh*16+l16), m'=wm*64+mf*16+l16,
// k=kk*32+kh*8+e. m' = oc*4+gate interleave.
__global__ __launch_bounds__(256) void repack_w_kernel(
    const float* __restrict__ w1, const float* __restrict__ w2, ushort_t* __restrict__ Wfrag)
{
    int id = blockIdx.x * 256 + threadIdx.x;
    if (id >= WFRAG_TOT) return;
    int e    = id & 7;
    int lane = (id >> 3) & 63;
    int mf   = (id >> 9) & 3;
    int wm   = (id >> 11) & 3;
    int kk   = (id >> 13) % 3;
    int tap  = (id / (3 << 13)) % 9;
    int br   = id / (9 * (3 << 13));
    int l16 = lane & 15, kh = lane >> 4;
    int m = wm * 64 + mf * 16 + l16;
    int k = kk * 32 + kh * 8 + e;
    int oc = m >> 2, gate = m & 3;
    const float* w = br ? w2 : w1;
    float v = (k < IND_ + HID_) ? w[((size_t)(gate * 64 + oc) * 89 + k) * 9 + tap] : 0.f;
    Wfrag[id] = f2bf(v);
}

// Repack final conv weights: src [oc=64][cin=128][ky][kx] fp32 -> Wc[tap][oc][k=128] bf16.
__global__ __launch_bounds__(256) void repack_wc_kernel(
    const float* __restrict__ wc, ushort_t* __restrict__ Wc)
{
    int id = blockIdx.x * 256 + threadIdx.x;
    if (id >= 9 * 64 * 128) return;
    int k   = id % 128;
    int oc  = (id / 128) % 64;
    int tap = id / (128 * 64);
    Wc[id] = f2bf(wc[((size_t)(oc * 128) + k) * 9 + tap]);
}

// LayerNorm for timestep t -> bf16 into both branches' current U buffers.
__global__ __launch_bounds__(256) void ln_t_kernel(
    const float* __restrict__ x, const float* __restrict__ gamma, const float* __restrict__ beta,
    ushort_t* __restrict__ U0, ushort_t* __restrict__ U1, int t)
{
    int p = blockIdx.x * 256 + threadIdx.x;
    if (p >= B_ * NPIX) return;
    int b = p / NPIX, hw = p % NPIX;
    int y = hw / 25, xx = hw % 25;
    const float* xp = x + ((size_t)(b * T_ + t) * IND_) * NPIX + hw;
    float v[IND_];
    float s = 0.f;
#pragma unroll
    for (int c = 0; c < IND_; ++c) { v[c] = xp[c * NPIX]; s += v[c]; }
    float mu = s * (1.f / IND_);
    float ss = 0.f;
#pragma unroll
    for (int c = 0; c < IND_; ++c) { float d = v[c] - mu; ss += d * d; }
    float rstd = rsqrtf(ss * (1.f / IND_) + 1e-5f);
    ushort_t* o0 = U0 + (size_t)b * UB0 + (size_t)((y + 1) * 27 + (xx + 1)) * KPAD;
    ushort_t* o1 = U1 + (size_t)b * UB1 + (size_t)((y + 2) * 29 + (xx + 2)) * KPAD;
#pragma unroll
    for (int c = 0; c < IND_; ++c) {
        ushort_t hv = f2bf((v[c] - mu) * rstd * gamma[c] + beta[c]);
        o0[c] = hv;
        o1[c] = hv;
    }
}

// One ConvLSTM timestep, both branches. B-tile staged in LDS (padded rows),
// A (weights) read dense from L2 in fragment order.
__global__ __launch_bounds__(512) void convlstm_mfma_kernel(
    const ushort_t* __restrict__ U0c, const ushort_t* __restrict__ U1c,
    ushort_t* __restrict__ U0n, ushort_t* __restrict__ U1n,
    const ushort_t* __restrict__ Wfrag,
    const float* __restrict__ bias1, const float* __restrict__ bias2,
    float* __restrict__ cst)
{
    const int rg = blockIdx.x;
    const int b  = blockIdx.y;
    const int br = blockIdx.z;
    const int d  = 1 + br;
    const int Wp = 25 + 2 * d;
    const ushort_t* __restrict__ Ucur = br ? (U1c + (size_t)b * UB1) : (U0c + (size_t)b * UB0);
    ushort_t* __restrict__ Unxt       = br ? (U1n + (size_t)b * UB1) : (U0n + (size_t)b * UB0);
    const float* __restrict__ bias = br ? bias2 : bias1;
    const ushort_t* __restrict__ WFb = Wfrag + (size_t)br * WFRAG_PER_BR;

    __shared__ ushort_t tile[LDSROWS * PADK];   // 61,360 B

    const int tid  = threadIdx.x;
    const int u0   = rg * 5 * Wp;
    const int R    = br ? 295 : 223;

    // ---- stage B-tile: global rows (stride 96) -> LDS rows (stride 104), coalesced 16B chunks
    {
        const ushort_t* src = Ucur + (size_t)u0 * KPAD;
        const int nchunk = R * 12;
        for (int i = tid; i < nchunk; i += 512) {
            const int row = i / 12, seg = i - row * 12;
            *(uint4*)(tile + row * PADK + seg * 8) = *(const uint4*)(src + row * KPAD + seg * 8);
        }
    }
    __syncthreads();

    const int w    = tid >> 6, lane = tid & 63;
    const int wm   = w & 3, wn = w >> 2;
    const int l16  = lane & 15, kh = lane >> 4;
    const int koff = kh * 8;

    f32x4 acc[4][5];
#pragma unroll
    for (int i = 0; i < 4; ++i)
#pragma unroll
        for (int j = 0; j < 5; ++j) acc[i][j] = (f32x4){0.f, 0.f, 0.f, 0.f};

    int baserel[5];
#pragma unroll
    for (int nf = 0; nf < 5; ++nf) {
        int n = wn * 80 + nf * 16 + l16;
        baserel[nf] = (n >> 5) * Wp + (n & 31);
    }

    for (int tap = 0; tap < 9; ++tap) {
        const int ky = tap / 3, kx = tap - 3 * ky;
        const int toff = (ky * Wp + kx) * d;
        const ushort_t* __restrict__ WT = WFb + (size_t)(tap * 3) * 8192 + wm * 2048 + lane * 8;
        int ldsb[5];
#pragma unroll
        for (int nf = 0; nf < 5; ++nf)
            ldsb[nf] = (baserel[nf] + toff) * PADK + koff;
#pragma unroll
        for (int kk = 0; kk < 3; ++kk) {
            bf16x8 af[4], bfr[5];
#pragma unroll
            for (int mf = 0; mf < 4; ++mf)
                af[mf] = *(const bf16x8*)(WT + (size_t)kk * 8192 + mf * 512);
#pragma unroll
            for (int nf = 0; nf < 5; ++nf)
                bfr[nf] = *(const bf16x8*)(tile + ldsb[nf] + kk * 32);
#pragma unroll
            for (int mf = 0; mf < 4; ++mf)
#pragma unroll
                for (int nf = 0; nf < 5; ++nf)
                    acc[mf][nf] = __builtin_amdgcn_mfma_f32_16x16x32_bf16(
                        af[mf], bfr[nf], acc[mf][nf], 0, 0, 0);
        }
    }

    // Epilogue: fused bias + gates + state update (C/D: col=lane&15, row=kh*4+reg, reg=gate).
#pragma unroll
    for (int mf = 0; mf < 4; ++mf) {
        const int oc = wm * 16 + mf * 4 + kh;
        const float bi = bias[oc], bff = bias[64 + oc], bo = bias[128 + oc], bg = bias[192 + oc];
#pragma unroll
        for (int nf = 0; nf < 5; ++nf) {
            const int n = wn * 80 + nf * 16 + l16;
            const int xx = n & 31;
            if (xx >= 25) continue;
            const int y = rg * 5 + (n >> 5);
            const int pix = y * 25 + xx;
            const size_t ci = ((size_t)((br * B_ + b) * HID_ + oc)) * NPIX + pix;
            const float zi = acc[mf][nf][0] + bi;
            const float zf = acc[mf][nf][1] + bff;
            const float zo = acc[mf][nf][2] + bo;
            const float zg = acc[mf][nf][3] + bg;
            const float co = cst[ci];
            const float cn = sigmoidf_(zf) * co + sigmoidf_(zi) * tanh_fast(zg);
            const float hn = sigmoidf_(zo) * tanh_fast(cn);
            cst[ci] = cn;
            Unxt[(size_t)((y + d) * Wp + (xx + d)) * KPAD + IND_ + oc] = f2bf(hn);
        }
    }
}

// Combine final hidden states into Hc[b][(y+1)*27+(x+1)][k=128] bf16.
__global__ __launch_bounds__(256) void combine_h_kernel(
    const ushort_t* __restrict__ U0, const ushort_t* __restrict__ U1, ushort_t* __restrict__ Hc)
{
    int id = blockIdx.x * 256 + threadIdx.x;
    if (id >= B_ * NPIX * 128) return;
    int k   = id % 128;
    int pix = (id / 128) % NPIX;
    int b   = id / (128 * NPIX);
    int y = pix / 25, xx = pix % 25;
    ushort_t v;
    if (k < 64) v = U0[(size_t)b * UB0 + (size_t)((y + 1) * 27 + (xx + 1)) * KPAD + IND_ + k];
    else        v = U1[(size_t)b * UB1 + (size_t)((y + 2) * 29 + (xx + 2)) * KPAD + IND_ + (k - 64)];
    Hc[(size_t)b * HCB + (size_t)((y + 1) * 27 + (xx + 1)) * 128 + k] = v;
}

// Final 3x3 conv (128->64, pad 1) + bias + ReLU via MFMA implicit-GEMM.
__global__ __launch_bounds__(512) void conv_mfma_kernel(
    const ushort_t* __restrict__ Hc, const ushort_t* __restrict__ Wc,
    const float* __restrict__ bc, float* __restrict__ conv_out)
{
    const int rg = blockIdx.x;
    const int b  = blockIdx.y;
    const ushort_t* __restrict__ Hb = Hc + (size_t)b * HCB;

    const int tid  = threadIdx.x;
    const int w    = tid >> 6, lane = tid & 63;
    const int wm   = w & 1, wn = w >> 1;
    const int l16  = lane & 15, kh = lane >> 4;
    const int koff = kh * 8;

    f32x4 acc[2][2];
#pragma unroll
    for (int i = 0; i < 2; ++i)
#pragma unroll
        for (int j = 0; j < 2; ++j) acc[i][j] = (f32x4){0.f, 0.f, 0.f, 0.f};

    int baserow[2];
#pragma unroll
    for (int nf = 0; nf < 2; ++nf) {
        int n = wn * 32 + nf * 16 + l16;
        baserow[nf] = (rg * 4 + (n >> 5)) * 27 + (n & 31);
    }
    const ushort_t* __restrict__ Wm = Wc + (size_t)(wm * 32 + l16) * 128 + koff;

    for (int tap = 0; tap < 9; ++tap) {
        const int ky = tap / 3, kx = tap - 3 * ky;
        const int toff = ky * 27 + kx;
        const ushort_t* __restrict__ Wt = Wm + (size_t)tap * (64 * 128);
        const ushort_t* Urow[2];
#pragma unroll
        for (int nf = 0; nf < 2; ++nf)
            Urow[nf] = Hb + (size_t)(baserow[nf] + toff) * 128 + koff;
#pragma unroll
        for (int kk = 0; kk < 4; ++kk) {
            bf16x8 af[2], bfr[2];
#pragma unroll
            for (int mf = 0; mf < 2; ++mf)
                af[mf] = *(const bf16x8*)(Wt + mf * 16 * 128 + kk * 32);
#pragma unroll
            for (int nf = 0; nf < 2; ++nf)
                bfr[nf] = *(const bf16x8*)(Urow[nf] + kk * 32);
#pragma unroll
            for (int mf = 0; mf < 2; ++mf)
#pragma unroll
                for (int nf = 0; nf < 2; ++nf)
                    acc[mf][nf] = __builtin_amdgcn_mfma_f32_16x16x32_bf16(
                        af[mf], bfr[nf], acc[mf][nf], 0, 0, 0);
        }
    }

#pragma unroll
    for (int mf = 0; mf < 2; ++mf) {
#pragma unroll
        for (int nf = 0; nf < 2; ++nf) {
            const int n = wn * 32 + nf * 16 + l16;
            const int xx = n & 31;
            if (xx >= 25) continue;
            const int y = rg * 4 + wn;
            if (y >= 25) continue;
#pragma unroll
            for (int r = 0; r < 4; ++r) {
                const int oc = wm * 32 + mf * 16 + kh * 4 + r;
                const float v = fmaxf(acc[mf][nf][r] + bc[oc], 0.f);
                conv_out[((size_t)(b * 64 + oc)) * NPIX + y * 25 + xx] = v;
            }
        }
    }
}

// 2x2/2 maxpool + torch-order flatten.
__global__ __launch_bounds__(256) void pool_kernel(
    const float* __restrict__ conv_out, float* __restrict__ pool)
{
    int id = blockIdx.x * 256 + threadIdx.x;
    if (id >= B_ * 64 * 144) return;
    int px = id % 12;
    int py = (id / 12) % 12;
    int oc = (id / 144) % 64;
    int b  = id / (144 * 64);
    const float* p = conv_out + ((size_t)(b * 64 + oc)) * NPIX;
    const int cy = 2 * py, cx = 2 * px;
    float mx = fmaxf(fmaxf(p[cy * 25 + cx], p[cy * 25 + cx + 1]),
                     fmaxf(p[(cy + 1) * 25 + cx], p[(cy + 1) * 25 + cx + 1]));
    pool[(size_t)b * 9216 + oc * 144 + py * 12 + px] = mx;
}

// fc1: one wave per (b, oc). Coalesced float4 loads + shuffle reduce.
__global__ __launch_bounds__(256) void fc1_kernel(
    const float* __restrict__ pool, const float* __restrict__ w1, const float* __restrict__ b1,
    float* __restrict__ f1)
{
    const int task = blockIdx.x * 4 + (threadIdx.x >> 6);
    const int lane = threadIdx.x & 63;
    const int b = task >> 6, oc = task & 63;
    const float* pr = pool + (size_t)b * 9216;
    const float* wr = w1 + (size_t)oc * 9216;
    float acc = 0.f;
#pragma unroll 4
    for (int it = 0; it < 36; ++it) {
        const int k = it * 256 + lane * 4;
        const float4 p = *(const float4*)(pr + k);
        const float4 ww = *(const float4*)(wr + k);
        acc += p.x * ww.x + p.y * ww.y + p.z * ww.z + p.w * ww.w;
    }
#pragma unroll
    for (int off = 32; off > 0; off >>= 1) acc += __shfl_down(acc, off);
    if (lane == 0) f1[b * 64 + oc] = fmaxf(acc + b1[oc], 0.f);
}

// fc2 + fc3 + log_softmax. One block per batch row, 64 threads.
__global__ __launch_bounds__(64) void head2_kernel(
    const float* __restrict__ f1,
    const float* __restrict__ w2, const float* __restrict__ b2,
    const float* __restrict__ w3, const float* __restrict__ b3,
    float* __restrict__ out)
{
    const int b = blockIdx.x;
    __shared__ float f1l[64];
    __shared__ float f2[32];
    const int tid = threadIdx.x;
    f1l[tid] = f1[b * 64 + tid];
    __syncthreads();
    if (tid < 32) {
        float acc = b2[tid];
        const float* wr = w2 + (size_t)tid * 64;
#pragma unroll
        for (int k = 0; k < 64; ++k) acc += f1l[k] * wr[k];
        f2[tid] = fmaxf(acc, 0.f);
    }
    __syncthreads();
    if (tid == 0) {
        float y0 = b3[0], y1 = b3[1];
#pragma unroll
        for (int k = 0; k < 32; ++k) { y0 += f2[k] * w3[k]; y1 += f2[k] * w3[32 + k]; }
        const float m = fmaxf(y0, y1);
        const float lse = m + logf(expf(y0 - m) + expf(y1 - m));
        out[b * 2 + 0] = y0 - lse;
        out[b * 2 + 1] = y1 - lse;
    }
}

extern "C" void kernel_launch(void* const* d_in, const int* in_sizes, int n_in,
                              void* d_out, int out_size, void* d_ws, size_t ws_size,
                              hipStream_t stream) {
    const float* x    = (const float*)d_in[0];
    const float* ln_g = (const float*)d_in[1];
    const float* ln_b = (const float*)d_in[2];
    const float* w_l1 = (const float*)d_in[3];
    const float* b_l1 = (const float*)d_in[4];
    const float* w_l2 = (const float*)d_in[5];
    const float* b_l2 = (const float*)d_in[6];
    const float* w_c  = (const float*)d_in[7];
    const float* b_c  = (const float*)d_in[8];
    const float* w_f1 = (const float*)d_in[9];
    const float* b_f1 = (const float*)d_in[10];
    const float* w_f2 = (const float*)d_in[11];
    const float* b_f2 = (const float*)d_in[12];
    const float* w_f3 = (const float*)d_in[13];
    const float* b_f3 = (const float*)d_in[14];

    // Workspace (ushort units unless noted):
    //   [0 .. UTOT)           U buffers bf16: U0A, U1A, U0B, U1B (A,A,B,B)
    //                         Hc (6.8M ushorts) aliases the dead B half after the loop.
    //   [UTOT .. +10.24M)     c state fp32 (5.12M floats); conv_out+pool alias it after loop.
    //   [.. +442,368)         Wfrag (lstm weights, fragment order)
    //   [.. +73,728)          Wc (conv weights)
    //   [.. +8,192)           f1 (fc1 output, 4096 floats)
    // Total ~62.4 MB.
    ushort_t* wsu = (ushort_t*)d_ws;
    float*    wsf = (float*)d_ws;
    uint_t*   wsi = (uint_t*)d_ws;

    ushort_t* U0A = wsu;
    ushort_t* U1A = wsu + USZ0;
    ushort_t* U0B = wsu + USZ0 + (size_t)USZ1;
    ushort_t* U1B = wsu + 2 * (size_t)USZ0 + USZ1;
    ushort_t* Hc  = U0B;
    float*    cst = wsf + (UTOT / 2);
    float*    conv_out = cst;
    float*    pool = cst + 2560000;
    ushort_t* Wfrag = wsu + UTOT + 10240000;
    ushort_t* Wc    = Wfrag + WFRAG_TOT;
    float*    f1    = (float*)(Wc + 73728);

    const int n_fill = (int)((UTOT * 2LL + 20480000) / 4);
    fill_zero_kernel<<<(n_fill + 255) / 256, 256, 0, stream>>>(wsi, n_fill);
    repack_w_kernel<<<(WFRAG_TOT + 255) / 256, 256, 0, stream>>>(w_l1, w_l2, Wfrag);
    repack_wc_kernel<<<(9 * 64 * 128 + 255) / 256, 256, 0, stream>>>(w_c, Wc);

    ushort_t* B0[2] = {U0A, U0B};
    ushort_t* B1[2] = {U1A, U1B};
    for (int t = 0; t < T_; ++t) {
        const int cur = t & 1, nxt = cur ^ 1;
        ln_t_kernel<<<(B_ * NPIX + 255) / 256, 256, 0, stream>>>(x, ln_g, ln_b, B0[cur], B1[cur], t);
        convlstm_mfma_kernel<<<dim3(5, B_, 2), 512, 0, stream>>>(
            B0[cur], B1[cur], B0[nxt], B1[nxt], Wfrag, b_l1, b_l2, cst);
    }
    fill_zero_kernel<<<(HCTOT / 2 + 255) / 256, 256, 0, stream>>>((uint_t*)Hc, HCTOT / 2);
    combine_h_kernel<<<(B_ * NPIX * 128 + 255) / 256, 256, 0, stream>>>(U0A, U1A, Hc);
    conv_mfma_kernel<<<dim3(7, B_), 512, 0, stream>>>(Hc, Wc, b_c, conv_out);
    pool_kernel<<<(B_ * 64 * 144 + 255) / 256, 256, 0, stream>>>(conv_out, pool);
    fc1_kernel<<<1024, 256, 0, stream>>>(pool, w_f1, b_f1, f1);
    head2_kernel<<<B_, 64, 0, stream>>>(f1, w_f2, b_f2, w_f3, b_f3, (float*)d_out);
}

// Round 5
// 2266.387 us; speedup vs baseline: 81.5092x; 1.0542x over previous
//
#include <hip/hip_runtime.h>
#include <hip/hip_bf16.h>
#include <math.h>

#define B_    64
#define T_    24
#define IND_  25
#define HID_  64
#define NPIX  625

// padded-grid geometry
#define WP0   27
#define WP1   29
#define XSTR  32          // x-buf row stride (ushorts)
#define HSTR  72          // h-buf row stride (ushorts) -> 144B rows, even bank-quad spread
#define XROWS0 744
#define XROWS1 856
#define HROWS0 744
#define HROWS1 856
#define XB0   (XROWS0*XSTR)   // 23,808 per batch
#define XB1   (XROWS1*XSTR)   // 27,392
#define HB0   (HROWS0*HSTR)   // 53,568 per batch
#define HB1   (HROWS1*HSTR)   // 61,632
#define XB0T  (B_*XB0)        // 1,523,712
#define XB1T  (B_*XB1)        // 1,753,088
#define HB0T  (B_*HB0)        // 3,428,352
#define HB1T  (B_*HB1)        // 3,944,448
#define UEND  (XB0T+XB1T+2*(HB0T+HB1T))   // 18,022,400 ushorts

// staged rows / chunks per branch (16B chunks, 9 per row)
#define RST0  200
#define RST1  272
#define CH0   (RST0*9)    // 1800
#define CH1   (RST1*9)    // 2448

// final-conv combined input: [b][832 rows][128] bf16
#define HCROWS 832
#define HCB    (HCROWS*128)
#define HCTOT  (B_*HCB)

#define WFRAG_PER_BR (9*3*4*4*512)    // 221,184
#define WFRAG_TOT    (2*WFRAG_PER_BR)

typedef __bf16 bf16x8 __attribute__((ext_vector_type(8)));
typedef float  f32x4  __attribute__((ext_vector_type(4)));
typedef unsigned short ushort_t;
typedef unsigned int   uint_t;

typedef const __attribute__((address_space(1))) void as1_cvoid;
typedef __attribute__((address_space(3))) void as3_void;

__device__ __forceinline__ float sigmoidf_(float x) { return 1.f / (1.f + __expf(-x)); }
__device__ __forceinline__ float tanh_fast(float x) { return 2.f / (1.f + __expf(-2.f * x)) - 1.f; }
__device__ __forceinline__ ushort_t f2bf(float f) {
    unsigned int u = __float_as_uint(f);
    u += 0x7FFFu + ((u >> 16) & 1u);
    return (ushort_t)(u >> 16);
}
__device__ __forceinline__ float bf2f(ushort_t h) {
    return __uint_as_float(((unsigned int)h) << 16);
}

__global__ __launch_bounds__(256) void fill_zero_kernel(uint_t* __restrict__ p, int n) {
    int i = blockIdx.x * 256 + threadIdx.x;
    if (i < n) p[i] = 0u;
}

// Wfrag[br][tap][kk][wm][mf][lane][e]: m-space m = wm*64 + gate*16 + ocl,
// gate = mf, oc = wm*16 + l16 (A-rows) / wm*16 + kh*4 + r (C/D rows).
// kk=0: k=kh*8+e -> c=k if k<25 else 0; kk=1: c=25+kh*8+e; kk=2: c=57+kh*8+e.
__global__ __launch_bounds__(256) void repack_w_kernel(
    const float* __restrict__ w1, const float* __restrict__ w2, ushort_t* __restrict__ Wfrag)
{
    int id = blockIdx.x * 256 + threadIdx.x;
    if (id >= WFRAG_TOT) return;
    int e    = id & 7;
    int lane = (id >> 3) & 63;
    int mf   = (id >> 9) & 3;
    int wm   = (id >> 11) & 3;
    int rest = id >> 13;
    int kk   = rest % 3;
    int tap  = (rest / 3) % 9;
    int br   = rest / 27;
    int l16 = lane & 15, kh = lane >> 4;
    int gate = mf;
    int oc   = wm * 16 + l16;
    int k    = kh * 8 + e;
    int c;
    if (kk == 0)      c = (k < IND_) ? k : -1;
    else if (kk == 1) c = IND_ + k;
    else              c = IND_ + 32 + k;
    const float* w = br ? w2 : w1;
    float v = (c >= 0) ? w[((size_t)(gate * 64 + oc) * 89 + c) * 9 + tap] : 0.f;
    Wfrag[id] = f2bf(v);
}

__global__ __launch_bounds__(256) void repack_wc_kernel(
    const float* __restrict__ wc, ushort_t* __restrict__ Wc)
{
    int id = blockIdx.x * 256 + threadIdx.x;
    if (id >= 9 * 64 * 128) return;
    int k   = id % 128;
    int oc  = (id / 128) % 64;
    int tap = id / (128 * 64);
    Wc[id] = f2bf(wc[((size_t)(oc * 128) + k) * 9 + tap]);
}

// LayerNorm for timestep t -> bf16 into both branches' x-bufs ([row][32] layout).
__global__ __launch_bounds__(256) void ln_t_kernel(
    const float* __restrict__ x, const float* __restrict__ gamma, const float* __restrict__ beta,
    ushort_t* __restrict__ xb0, ushort_t* __restrict__ xb1, int t)
{
    int p = blockIdx.x * 256 + threadIdx.x;
    if (p >= B_ * NPIX) return;
    int b = p / NPIX, hw = p % NPIX;
    int y = hw / 25, xx = hw % 25;
    const float* xp = x + ((size_t)(b * T_ + t) * IND_) * NPIX + hw;
    float v[IND_];
    float s = 0.f;
#pragma unroll
    for (int c = 0; c < IND_; ++c) { v[c] = xp[c * NPIX]; s += v[c]; }
    float mu = s * (1.f / IND_);
    float ss = 0.f;
#pragma unroll
    for (int c = 0; c < IND_; ++c) { float d = v[c] - mu; ss += d * d; }
    float rstd = rsqrtf(ss * (1.f / IND_) + 1e-5f);
    ushort_t* o0 = xb0 + (size_t)b * XB0 + (size_t)((y + 1) * WP0 + (xx + 1)) * XSTR;
    ushort_t* o1 = xb1 + (size_t)b * XB1 + (size_t)((y + 2) * WP1 + (xx + 2)) * XSTR;
#pragma unroll
    for (int c = 0; c < IND_; ++c) {
        ushort_t hv = f2bf((v[c] - mu) * rstd * gamma[c] + beta[c]);
        o0[c] = hv;
        o1[c] = hv;
    }
}

// One ConvLSTM timestep, both branches. h-tile async-staged into LDS via
// global_load_lds (linear copy, h-buf IS the LDS image); x B-fragments from global.
__global__ __launch_bounds__(512) void convlstm_mfma_kernel(
    const ushort_t* __restrict__ xb0g, const ushort_t* __restrict__ xb1g,
    const ushort_t* __restrict__ h0c, const ushort_t* __restrict__ h1c,
    ushort_t* __restrict__ h0n, ushort_t* __restrict__ h1n,
    const ushort_t* __restrict__ Wfrag,
    const float* __restrict__ bias1, const float* __restrict__ bias2,
    float* __restrict__ cst, int t)
{
    const int rg = blockIdx.x;
    const int b  = blockIdx.y;
    const int br = blockIdx.z;
    const int d  = 1 + br;
    const int Wp = br ? WP1 : WP0;
    const ushort_t* __restrict__ xb = (br ? xb1g + (size_t)b * XB1 : xb0g + (size_t)b * XB0);
    const ushort_t* __restrict__ hc = (br ? h1c + (size_t)b * HB1 : h0c + (size_t)b * HB0);
    ushort_t* __restrict__ hn       = (br ? h1n + (size_t)b * HB1 : h0n + (size_t)b * HB0);
    const float* __restrict__ bias = br ? bias2 : bias1;
    const ushort_t* __restrict__ WFb = Wfrag + (size_t)br * WFRAG_PER_BR;

    __shared__ ushort_t tile[RST1 * HSTR];   // 19,584 ushorts = 39,168 B

    const int tid = threadIdx.x;
    const int u0  = rg * 5 * Wp;
    const int CH  = br ? CH1 : CH0;

    // ---- async stage h-tile: pure linear 16B-chunk copy, no VGPR round-trip
    {
        const char* gsrc = (const char*)(hc + (size_t)u0 * HSTR);
        const int wave_u = tid & 448;   // w*64
#pragma unroll
        for (int j = 0; j < 5; ++j) {
            const int i = j * 512 + tid;
            if (i < CH) {
                __builtin_amdgcn_global_load_lds(
                    (as1_cvoid*)(gsrc + (size_t)i * 16),
                    (as3_void*)((char*)tile + (size_t)(j * 512 + wave_u) * 16),
                    16, 0, 0);
            }
        }
    }
    __syncthreads();

    const int w    = tid >> 6, lane = tid & 63;
    const int wm   = w & 3, wn = w >> 2;
    const int l16  = lane & 15, kh = lane >> 4;
    const int koff = kh * 8;

    f32x4 acc[4][5];
#pragma unroll
    for (int i = 0; i < 4; ++i)
#pragma unroll
        for (int j = 0; j < 5; ++j) acc[i][j] = (f32x4){0.f, 0.f, 0.f, 0.f};

    int baserel[5];
#pragma unroll
    for (int nf = 0; nf < 5; ++nf) {
        int n = wn * 80 + nf * 16 + l16;
        baserel[nf] = (n >> 5) * Wp + (n & 31);
    }

    for (int tap = 0; tap < 9; ++tap) {
        const int ky = tap / 3, kx = tap - 3 * ky;
        const int toff = (ky * Wp + kx) * d;
        const ushort_t* __restrict__ WT = WFb + (size_t)(tap * 3) * 8192 + wm * 2048 + lane * 8;

        // kk = 0: x chunk (B from global x-buf)
        {
            bf16x8 af[4], bfr[5];
#pragma unroll
            for (int mf = 0; mf < 4; ++mf)
                af[mf] = *(const bf16x8*)(WT + mf * 512);
#pragma unroll
            for (int nf = 0; nf < 5; ++nf)
                bfr[nf] = *(const bf16x8*)(xb + (size_t)(u0 + baserel[nf] + toff) * XSTR + koff);
#pragma unroll
            for (int mf = 0; mf < 4; ++mf)
#pragma unroll
                for (int nf = 0; nf < 5; ++nf)
                    acc[mf][nf] = __builtin_amdgcn_mfma_f32_16x16x32_bf16(
                        af[mf], bfr[nf], acc[mf][nf], 0, 0, 0);
        }
        // kk = 1,2: h chunks (B from LDS)
#pragma unroll
        for (int kkh = 0; kkh < 2; ++kkh) {
            bf16x8 af[4], bfr[5];
#pragma unroll
            for (int mf = 0; mf < 4; ++mf)
                af[mf] = *(const bf16x8*)(WT + (size_t)(kkh + 1) * 8192 + mf * 512);
#pragma unroll
            for (int nf = 0; nf < 5; ++nf)
                bfr[nf] = *(const bf16x8*)(tile + (baserel[nf] + toff) * HSTR + kkh * 32 + koff);
#pragma unroll
            for (int mf = 0; mf < 4; ++mf)
#pragma unroll
                for (int nf = 0; nf < 5; ++nf)
                    acc[mf][nf] = __builtin_amdgcn_mfma_f32_16x16x32_bf16(
                        af[mf], bfr[nf], acc[mf][nf], 0, 0, 0);
        }
    }

    // Epilogue: gates are mf (0..3); C/D reg r -> oc = wm*16 + kh*4 + r (4 consecutive oc).
    const int oc0 = wm * 16 + kh * 4;
    float bi4[4], bf4[4], bo4[4], bg4[4];
#pragma unroll
    for (int r = 0; r < 4; ++r) {
        bi4[r] = bias[oc0 + r];
        bf4[r] = bias[64 + oc0 + r];
        bo4[r] = bias[128 + oc0 + r];
        bg4[r] = bias[192 + oc0 + r];
    }
#pragma unroll
    for (int nf = 0; nf < 5; ++nf) {
        const int n = wn * 80 + nf * 16 + l16;
        const int xx = n & 31;
        if (xx >= 25) continue;
        const int y = rg * 5 + (n >> 5);
        const int pix = y * 25 + xx;
        const size_t cbase = ((size_t)((br * B_ + b) * HID_) + oc0) * NPIX + pix;
        ushort_t hs[4];
#pragma unroll
        for (int r = 0; r < 4; ++r) {
            const float zi = acc[0][nf][r] + bi4[r];
            const float zf = acc[1][nf][r] + bf4[r];
            const float zo = acc[2][nf][r] + bo4[r];
            const float zg = acc[3][nf][r] + bg4[r];
            float co = 0.f;
            if (t != 0) co = cst[cbase + (size_t)r * NPIX];
            const float cn = sigmoidf_(zf) * co + sigmoidf_(zi) * tanh_fast(zg);
            cst[cbase + (size_t)r * NPIX] = cn;
            hs[r] = f2bf(sigmoidf_(zo) * tanh_fast(cn));
        }
        uint2 hv;
        hv.x = (uint_t)hs[0] | ((uint_t)hs[1] << 16);
        hv.y = (uint_t)hs[2] | ((uint_t)hs[3] << 16);
        *(uint2*)(hn + (size_t)((y + d) * Wp + (xx + d)) * HSTR + oc0) = hv;
    }
}

// Combine final hidden states into Hc[b][(y+1)*27+(x+1)][k=128] bf16.
__global__ __launch_bounds__(256) void combine_h_kernel(
    const ushort_t* __restrict__ h0, const ushort_t* __restrict__ h1, ushort_t* __restrict__ Hc)
{
    int id = blockIdx.x * 256 + threadIdx.x;
    if (id >= B_ * NPIX * 128) return;
    int k   = id % 128;
    int pix = (id / 128) % NPIX;
    int b   = id / (128 * NPIX);
    int y = pix / 25, xx = pix % 25;
    ushort_t v;
    if (k < 64) v = h0[(size_t)b * HB0 + (size_t)((y + 1) * WP0 + (xx + 1)) * HSTR + k];
    else        v = h1[(size_t)b * HB1 + (size_t)((y + 2) * WP1 + (xx + 2)) * HSTR + (k - 64)];
    Hc[(size_t)b * HCB + (size_t)((y + 1) * 27 + (xx + 1)) * 128 + k] = v;
}

// Final 3x3 conv (128->64, pad 1) + bias + ReLU via MFMA implicit-GEMM.
__global__ __launch_bounds__(512) void conv_mfma_kernel(
    const ushort_t* __restrict__ Hc, const ushort_t* __restrict__ Wc,
    const float* __restrict__ bc, float* __restrict__ conv_out)
{
    const int rg = blockIdx.x;
    const int b  = blockIdx.y;
    const ushort_t* __restrict__ Hb = Hc + (size_t)b * HCB;

    const int tid  = threadIdx.x;
    const int w    = tid >> 6, lane = tid & 63;
    const int wm   = w & 1, wn = w >> 1;
    const int l16  = lane & 15, kh = lane >> 4;
    const int koff = kh * 8;

    f32x4 acc[2][2];
#pragma unroll
    for (int i = 0; i < 2; ++i)
#pragma unroll
        for (int j = 0; j < 2; ++j) acc[i][j] = (f32x4){0.f, 0.f, 0.f, 0.f};

    int baserow[2];
#pragma unroll
    for (int nf = 0; nf < 2; ++nf) {
        int n = wn * 32 + nf * 16 + l16;
        baserow[nf] = (rg * 4 + (n >> 5)) * 27 + (n & 31);
    }
    const ushort_t* __restrict__ Wm = Wc + (size_t)(wm * 32 + l16) * 128 + koff;

    for (int tap = 0; tap < 9; ++tap) {
        const int ky = tap / 3, kx = tap - 3 * ky;
        const int toff = ky * 27 + kx;
        const ushort_t* __restrict__ Wt = Wm + (size_t)tap * (64 * 128);
        const ushort_t* Urow[2];
#pragma unroll
        for (int nf = 0; nf < 2; ++nf)
            Urow[nf] = Hb + (size_t)(baserow[nf] + toff) * 128 + koff;
#pragma unroll
        for (int kk = 0; kk < 4; ++kk) {
            bf16x8 af[2], bfr[2];
#pragma unroll
            for (int mf = 0; mf < 2; ++mf)
                af[mf] = *(const bf16x8*)(Wt + mf * 16 * 128 + kk * 32);
#pragma unroll
            for (int nf = 0; nf < 2; ++nf)
                bfr[nf] = *(const bf16x8*)(Urow[nf] + kk * 32);
#pragma unroll
            for (int mf = 0; mf < 2; ++mf)
#pragma unroll
                for (int nf = 0; nf < 2; ++nf)
                    acc[mf][nf] = __builtin_amdgcn_mfma_f32_16x16x32_bf16(
                        af[mf], bfr[nf], acc[mf][nf], 0, 0, 0);
        }
    }

#pragma unroll
    for (int mf = 0; mf < 2; ++mf) {
#pragma unroll
        for (int nf = 0; nf < 2; ++nf) {
            const int n = wn * 32 + nf * 16 + l16;
            const int xx = n & 31;
            if (xx >= 25) continue;
            const int y = rg * 4 + wn;
            if (y >= 25) continue;
#pragma unroll
            for (int r = 0; r < 4; ++r) {
                const int oc = wm * 32 + mf * 16 + kh * 4 + r;
                const float v = fmaxf(acc[mf][nf][r] + bc[oc], 0.f);
                conv_out[((size_t)(b * 64 + oc)) * NPIX + y * 25 + xx] = v;
            }
        }
    }
}

__global__ __launch_bounds__(256) void pool_kernel(
    const float* __restrict__ conv_out, float* __restrict__ pool)
{
    int id = blockIdx.x * 256 + threadIdx.x;
    if (id >= B_ * 64 * 144) return;
    int px = id % 12;
    int py = (id / 12) % 12;
    int oc = (id / 144) % 64;
    int b  = id / (144 * 64);
    const float* p = conv_out + ((size_t)(b * 64 + oc)) * NPIX;
    const int cy = 2 * py, cx = 2 * px;
    float mx = fmaxf(fmaxf(p[cy * 25 + cx], p[cy * 25 + cx + 1]),
                     fmaxf(p[(cy + 1) * 25 + cx], p[(cy + 1) * 25 + cx + 1]));
    pool[(size_t)b * 9216 + oc * 144 + py * 12 + px] = mx;
}

__global__ __launch_bounds__(256) void fc1_kernel(
    const float* __restrict__ pool, const float* __restrict__ w1, const float* __restrict__ b1,
    float* __restrict__ f1)
{
    const int task = blockIdx.x * 4 + (threadIdx.x >> 6);
    const int lane = threadIdx.x & 63;
    const int b = task >> 6, oc = task & 63;
    const float* pr = pool + (size_t)b * 9216;
    const float* wr = w1 + (size_t)oc * 9216;
    float acc = 0.f;
#pragma unroll 4
    for (int it = 0; it < 36; ++it) {
        const int k = it * 256 + lane * 4;
        const float4 p = *(const float4*)(pr + k);
        const float4 ww = *(const float4*)(wr + k);
        acc += p.x * ww.x + p.y * ww.y + p.z * ww.z + p.w * ww.w;
    }
#pragma unroll
    for (int off = 32; off > 0; off >>= 1) acc += __shfl_down(acc, off);
    if (lane == 0) f1[b * 64 + oc] = fmaxf(acc + b1[oc], 0.f);
}

__global__ __launch_bounds__(64) void head2_kernel(
    const float* __restrict__ f1,
    const float* __restrict__ w2, const float* __restrict__ b2,
    const float* __restrict__ w3, const float* __restrict__ b3,
    float* __restrict__ out)
{
    const int b = blockIdx.x;
    __shared__ float f1l[64];
    __shared__ float f2[32];
    const int tid = threadIdx.x;
    f1l[tid] = f1[b * 64 + tid];
    __syncthreads();
    if (tid < 32) {
        float acc = b2[tid];
        const float* wr = w2 + (size_t)tid * 64;
#pragma unroll
        for (int k = 0; k < 64; ++k) acc += f1l[k] * wr[k];
        f2[tid] = fmaxf(acc, 0.f);
    }
    __syncthreads();
    if (tid == 0) {
        float y0 = b3[0], y1 = b3[1];
#pragma unroll
        for (int k = 0; k < 32; ++k) { y0 += f2[k] * w3[k]; y1 += f2[k] * w3[32 + k]; }
        const float m = fmaxf(y0, y1);
        const float lse = m + logf(expf(y0 - m) + expf(y1 - m));
        out[b * 2 + 0] = y0 - lse;
        out[b * 2 + 1] = y1 - lse;
    }
}

extern "C" void kernel_launch(void* const* d_in, const int* in_sizes, int n_in,
                              void* d_out, int out_size, void* d_ws, size_t ws_size,
                              hipStream_t stream) {
    const float* x    = (const float*)d_in[0];
    const float* ln_g = (const float*)d_in[1];
    const float* ln_b = (const float*)d_in[2];
    const float* w_l1 = (const float*)d_in[3];
    const float* b_l1 = (const float*)d_in[4];
    const float* w_l2 = (const float*)d_in[5];
    const float* b_l2 = (const float*)d_in[6];
    const float* w_c  = (const float*)d_in[7];
    const float* b_c  = (const float*)d_in[8];
    const float* w_f1 = (const float*)d_in[9];
    const float* b_f1 = (const float*)d_in[10];
    const float* w_f2 = (const float*)d_in[11];
    const float* b_f2 = (const float*)d_in[12];
    const float* w_f3 = (const float*)d_in[13];
    const float* b_f3 = (const float*)d_in[14];

    // Workspace (ushort offsets):
    //   xb0 @0 (1,523,712) | xb1 (1,753,088) | h0A (3,428,352) | h1A (3,944,448)
    //   | h0B | h1B  -> UEND = 18,022,400 ush = 36.0 MB
    //   cst fp32 @UEND (5,120,000 f = 20.5 MB); conv_out+pool alias it after loop
    //   Wfrag @ UEND+10,240,000 ush; Wc; f1. Hc aliases h0B (B half dead at end).
    // Total ~57.6 MB.
    ushort_t* wsu = (ushort_t*)d_ws;
    uint_t*   wsi = (uint_t*)d_ws;

    ushort_t* xb0 = wsu;
    ushort_t* xb1 = xb0 + XB0T;
    ushort_t* h0A = xb1 + XB1T;
    ushort_t* h1A = h0A + HB0T;
    ushort_t* h0B = h1A + HB1T;
    ushort_t* h1B = h0B + HB0T;
    float*    cst = (float*)(wsu + UEND);
    float*    conv_out = cst;
    float*    pool = cst + 2560000;
    ushort_t* Wfrag = wsu + UEND + 10240000;
    ushort_t* Wc    = Wfrag + WFRAG_TOT;
    float*    f1    = (float*)(Wc + 73728);
    ushort_t* Hc    = h0B;

    // zero x-bufs + h-bufs (borders must be 0; h0A/h1A are h0=0 state). cst handled via t==0.
    fill_zero_kernel<<<(UEND / 2 + 255) / 256, 256, 0, stream>>>(wsi, UEND / 2);
    repack_w_kernel<<<(WFRAG_TOT + 255) / 256, 256, 0, stream>>>(w_l1, w_l2, Wfrag);
    repack_wc_kernel<<<(9 * 64 * 128 + 255) / 256, 256, 0, stream>>>(w_c, Wc);

    ushort_t* H0[2] = {h0A, h0B};
    ushort_t* H1[2] = {h1A, h1B};
    for (int t = 0; t < T_; ++t) {
        const int cur = t & 1, nxt = cur ^ 1;
        ln_t_kernel<<<(B_ * NPIX + 255) / 256, 256, 0, stream>>>(x, ln_g, ln_b, xb0, xb1, t);
        convlstm_mfma_kernel<<<dim3(5, B_, 2), 512, 0, stream>>>(
            xb0, xb1, H0[cur], H1[cur], H0[nxt], H1[nxt], Wfrag, b_l1, b_l2, cst, t);
    }
    // final h in parity-0 (A). Hc overwrites dead B half: zero it first.
    fill_zero_kernel<<<(HCTOT / 2 + 255) / 256, 256, 0, stream>>>((uint_t*)Hc, HCTOT / 2);
    combine_h_kernel<<<(B_ * NPIX * 128 + 255) / 256, 256, 0, stream>>>(h0A, h1A, Hc);
    conv_mfma_kernel<<<dim3(7, B_), 512, 0, stream>>>(Hc, Wc, b_c, conv_out);
    pool_kernel<<<(B_ * 64 * 144 + 255) / 256, 256, 0, stream>>>(conv_out, pool);
    fc1_kernel<<<1024, 256, 0, stream>>>(pool, w_f1, b_f1, f1);
    head2_kernel<<<B_, 64, 0, stream>>>(f1, w_f2, b_f2, w_f3, b_f3, (float*)d_out);
}